// Round 1
// baseline (145.132 us; speedup 1.0000x reference)
//
#include <hip/hip_runtime.h>

namespace {

constexpr int H = 128, W = 128, T = 4;
constexpr int HWT = H * W * T;
constexpr int RAD = 2;
constexpr float GAMMA_W = 3.3257199f;

__global__ __launch_bounds__(256) void statden_kernel(
    const float* __restrict__ noisy,
    const float* __restrict__ guid,
    const float* __restrict__ est,
    const float* __restrict__ var,
    float* __restrict__ out)
{
    const int idx = blockIdx.x * 256 + threadIdx.x;
    const int t = idx & (T - 1);
    const int w = (idx >> 2) & (W - 1);
    const int h = idx >> 9;

    // center values
    float gc[9];
#pragma unroll
    for (int c = 0; c < 9; ++c) gc[c] = guid[c * HWT + idx];
    float ec[3], vc[3];
#pragma unroll
    for (int c = 0; c < 3; ++c) {
        ec[c] = est[c * HWT + idx];
        vc[c] = var[c * HWT + idx];
    }

    const float sig[9] = {0.1f, 0.1f, 0.1f, 50.f, 50.f, 50.f, 10.f, 10.f, 10.f};

    float acc0 = 0.f, acc1 = 0.f, acc2 = 0.f, denom = 0.f;

    for (int di = -RAD; di <= RAD; ++di) {
        const int hh = h + di;
        const bool okh = (unsigned)hh < (unsigned)H;
        for (int dj = -RAD; dj <= RAD; ++dj) {
            const int ww = w + dj;
            const bool okhw = okh && ((unsigned)ww < (unsigned)W);
            const int base = (hh * W + ww) * T;
#pragma unroll
            for (int dk = -RAD; dk <= RAD; ++dk) {
                const int tt = t + dk;
                const bool ib = okhw && ((unsigned)tt < (unsigned)T);
                // clamp index to 0 for OOB; mask loaded values to zero.
                const int nidx = ib ? (base + tt) : 0;
                const float zm = ib ? 1.0f : 0.0f;

                // guidance bilateral weight: exp(-0.5 * sum_c sig[c]*(gj-gc)^2)
                float s = 0.f;
#pragma unroll
                for (int c = 0; c < 9; ++c) {
                    const float gj = guid[c * HWT + nidx] * zm;
                    const float d = gj - gc[c];
                    s += sig[c] * d * d;
                }

                // membership: all 3 estimand channels must pass the t-test
                bool member = true;
#pragma unroll
                for (int c = 0; c < 3; ++c) {
                    const float ei = ec[c], vi = vc[c];
                    const float ej = est[c * HWT + nidx] * zm;
                    const float vj = var[c * HWT + nidx] * zm;
                    const float d = ei - ej;
                    const float d2 = d * d;
                    const float den = 2.0f * (d2 + vi + vj);
                    float wgt = (den == 0.0f) ? 0.5f : (2.0f * d2 + vi + vj) / den;
                    if (((vi == 0.0f) || (vj == 0.0f)) && (ei != ej)) wgt = 1.0f;
                    bool memc;
                    if (wgt >= 1.0f) {
                        memc = false;  // t = inf
                    } else {
                        const float ws = fminf(wgt, 1.0f - 1e-7f);
                        const float t2 = fmaxf(1.0f / (2.0f * (1.0f - ws)) - 1.0f, 0.0f);
                        memc = (sqrtf(t2) <= GAMMA_W);
                    }
                    member = member && memc;
                }

                const float fw = member ? expf(-0.5f * s) : 0.0f;

                // NOTE: OOB neighbors DO contribute fw to the denominator
                // (reference sums fw over all 125 patches); only their noisy
                // value is zero.
                denom += fw;
                acc0 = fmaf(fw, noisy[0 * HWT + nidx] * zm, acc0);
                acc1 = fmaf(fw, noisy[1 * HWT + nidx] * zm, acc1);
                acc2 = fmaf(fw, noisy[2 * HWT + nidx] * zm, acc2);
            }
        }
    }

    const float inv = 1.0f / fmaxf(denom, 1e-12f);
    out[0 * HWT + idx] = acc0 * inv;
    out[1 * HWT + idx] = acc1 * inv;
    out[2 * HWT + idx] = acc2 * inv;
}

} // namespace

extern "C" void kernel_launch(void* const* d_in, const int* in_sizes, int n_in,
                              void* d_out, int out_size, void* d_ws, size_t ws_size,
                              hipStream_t stream)
{
    const float* noisy = (const float*)d_in[0];
    const float* guid  = (const float*)d_in[1];
    const float* est   = (const float*)d_in[2];
    const float* var   = (const float*)d_in[3];
    float* out = (float*)d_out;

    statden_kernel<<<HWT / 256, 256, 0, stream>>>(noisy, guid, est, var, out);
}

// Round 2
// 24.531 us; speedup vs baseline: 5.9162x; 5.9162x over previous
//
#include <hip/hip_runtime.h>

namespace {

constexpr int H = 128, W = 128;
constexpr int NPIX = H * W;          // 16384
constexpr float GAMMA_W = 3.3257199f;

__device__ __forceinline__ void load4(const float4* __restrict__ p, float o[4]) {
    const float4 v = *p;
    o[0] = v.x; o[1] = v.y; o[2] = v.z; o[3] = v.w;
}

// block = 64 pixels x 5 di-slices = 320 threads (5 waves)
__global__ __launch_bounds__(320, 2) void statden(
    const float4* __restrict__ noisy,   // [3][NPIX]
    const float4* __restrict__ guid,    // [9][NPIX]
    const float4* __restrict__ est,     // [3][NPIX]
    const float4* __restrict__ var,     // [3][NPIX]
    float4* __restrict__ out)           // [3][NPIX]
{
    const float sig[9] = {0.1f, 0.1f, 0.1f, 50.f, 50.f, 50.f, 10.f, 10.f, 10.f};
    // t(w) <= gamma  <=>  w <= 1 - 1/(2*(gamma^2+1))
    const float WMAX = (float)(1.0 - 1.0 / (2.0 * ((double)GAMMA_W * (double)GAMMA_W + 1.0)));

    const int tid = threadIdx.x;
    const int p   = tid & 63;           // pixel lane within block
    const int s   = tid >> 6;           // di slice 0..4
    const int pid = blockIdx.x * 64 + p;
    const int h   = pid >> 7;
    const int w   = pid & 127;

    // ---- center (hoisted): sig*gc, qc = sum sig*gc^2, est/var centers ----
    float sgc[9][4], qc[4] = {0.f, 0.f, 0.f, 0.f};
    float ecv[3][4], vcv[3][4];
    {
        float g[4];
#pragma unroll
        for (int c = 0; c < 9; ++c) {
            load4(guid + c * NPIX + pid, g);
#pragma unroll
            for (int t = 0; t < 4; ++t) {
                sgc[c][t] = sig[c] * g[t];
                qc[t] += sgc[c][t] * g[t];
            }
        }
#pragma unroll
        for (int c = 0; c < 3; ++c) {
            load4(est + c * NPIX + pid, ecv[c]);
            load4(var + c * NPIX + pid, vcv[c]);
        }
    }

    float acc[3][4] = {};
    float den[4] = {0.f, 0.f, 0.f, 0.f};

    const int hh = h + s - 2;
    if ((unsigned)hh < (unsigned)H) {
#pragma unroll
        for (int dj = -2; dj <= 2; ++dj) {
            const int ww = w + dj;
            if ((unsigned)ww >= (unsigned)W) continue;
            const int q = hh * W + ww;

            float gj[9][4], ej[3][4], vj[3][4], nj[3][4];
#pragma unroll
            for (int c = 0; c < 9; ++c) load4(guid + c * NPIX + q, gj[c]);
#pragma unroll
            for (int c = 0; c < 3; ++c) {
                load4(est   + c * NPIX + q, ej[c]);
                load4(var   + c * NPIX + q, vj[c]);
                load4(noisy + c * NPIX + q, nj[c]);
            }

#pragma unroll
            for (int tt = 0; tt < 4; ++tt) {
                // qj = sum_c sig*gj^2 ; cross[t] = sum_c gj*(sig*gc)
                float qj = 0.f;
#pragma unroll
                for (int c = 0; c < 9; ++c) qj += sig[c] * gj[c][tt] * gj[c][tt];
                float cross[4] = {0.f, 0.f, 0.f, 0.f};
#pragma unroll
                for (int c = 0; c < 9; ++c) {
                    const float gv = gj[c][tt];
#pragma unroll
                    for (int t = 0; t < 4; ++t) cross[t] += gv * sgc[c][t];
                }
#pragma unroll
                for (int t = 0; t < 4; ++t) {
                    if (tt - t > 2 || t - tt > 2) continue;   // |dk|>2: not a patch
                    const float sv = qj + qc[t] - 2.f * cross[t];
                    bool member = true;
#pragma unroll
                    for (int c = 0; c < 3; ++c) {
                        const float ejv = ej[c][tt], vjv = vj[c][tt];
                        const float d   = ecv[c][t] - ejv;
                        const float d2  = d * d;
                        const float S   = vcv[c][t] + vjv;
                        const float num = 2.f * d2 + S;
                        const float dn  = num + S;          // = 2*(d2 + vi + vj)
                        bool pass = (num <= WMAX * dn);     // den==0 -> 0<=0 pass (w=0.5)
                        if (((vcv[c][t] == 0.f) || (vjv == 0.f)) && (d != 0.f)) pass = false;
                        member = member && pass;
                    }
                    const float f = member ? __expf(-0.5f * sv) : 0.f;
                    den[t] += f;
#pragma unroll
                    for (int c = 0; c < 3; ++c) acc[c][t] += f * nj[c][tt];
                }
            }
        }
    }

    // ---- reduce the 5 di-slices via LDS ----
    __shared__ float red[5][64][16];
    {
        float* r = &red[s][p][0];
#pragma unroll
        for (int c = 0; c < 3; ++c)
#pragma unroll
            for (int t = 0; t < 4; ++t) r[c * 4 + t] = acc[c][t];
#pragma unroll
        for (int t = 0; t < 4; ++t) r[12 + t] = den[t];
    }
    __syncthreads();

    if (tid < 64) {
#pragma unroll
        for (int k = 1; k < 5; ++k) {
            const float* r2 = &red[k][p][0];
#pragma unroll
            for (int c = 0; c < 3; ++c)
#pragma unroll
                for (int t = 0; t < 4; ++t) acc[c][t] += r2[c * 4 + t];
#pragma unroll
            for (int t = 0; t < 4; ++t) den[t] += r2[12 + t];
        }

        // ---- OOB (zero-padded) patches: member iff all ec==0; bw = exp(-qc/2) ----
        const int nh  = min(h + 2, H - 1) - max(h - 2, 0) + 1;
        const int nw  = min(w + 2, W - 1) - max(w - 2, 0) + 1;
        const int nhw = nh * nw;
        const int ntt[4] = {3, 4, 4, 3};
#pragma unroll
        for (int t = 0; t < 4; ++t) {
            const int oob = 125 - nhw * ntt[t];
            const bool allz = (ecv[0][t] == 0.f) && (ecv[1][t] == 0.f) && (ecv[2][t] == 0.f);
            const float f = allz ? __expf(-0.5f * qc[t]) : 0.f;
            den[t] += (float)oob * f;
        }

        float ot[3][4];
#pragma unroll
        for (int t = 0; t < 4; ++t) {
            const float inv = 1.0f / fmaxf(den[t], 1e-12f);
#pragma unroll
            for (int c = 0; c < 3; ++c) ot[c][t] = acc[c][t] * inv;
        }
#pragma unroll
        for (int c = 0; c < 3; ++c) {
            float4 v;
            v.x = ot[c][0]; v.y = ot[c][1]; v.z = ot[c][2]; v.w = ot[c][3];
            out[c * NPIX + pid] = v;
        }
    }
}

} // namespace

extern "C" void kernel_launch(void* const* d_in, const int* in_sizes, int n_in,
                              void* d_out, int out_size, void* d_ws, size_t ws_size,
                              hipStream_t stream)
{
    const float4* noisy = (const float4*)d_in[0];
    const float4* guid  = (const float4*)d_in[1];
    const float4* est   = (const float4*)d_in[2];
    const float4* var   = (const float4*)d_in[3];
    float4* out = (float4*)d_out;

    statden<<<NPIX / 64, 320, 0, stream>>>(noisy, guid, est, var, out);
}